// Round 11
// baseline (147.265 us; speedup 1.0000x reference)
//
#include <hip/hip_runtime.h>

#define D 96
#define D4 24
#define NXCD 8
#define CAP 64    // slots per node; P(Poisson(16) >= 64) ~ 1e-18

typedef unsigned int uint32;
typedef unsigned short ushort16;
typedef int int4v __attribute__((ext_vector_type(4)));   // clang vector (NT-load ok)

// Round-to-nearest-even f32 -> bf16, packed pair.
__device__ __forceinline__ uint32 pk_bf16(float a, float b) {
    uint32 ua = __float_as_uint(a);
    uint32 ub = __float_as_uint(b);
    ua = (ua + 0x7fffu + ((ua >> 16) & 1u)) >> 16;
    ub = (ub + 0x7fffu + ((ub >> 16) & 1u)) & 0xffff0000u;
    return (ua & 0xffffu) | ub;
}

#define UNPK_ADD(u, o) \
    acc[(o)+0] += __uint_as_float((u).x << 16); \
    acc[(o)+1] += __uint_as_float((u).x & 0xffff0000u); \
    acc[(o)+2] += __uint_as_float((u).y << 16); \
    acc[(o)+3] += __uint_as_float((u).y & 0xffff0000u); \
    acc[(o)+4] += __uint_as_float((u).z << 16); \
    acc[(o)+5] += __uint_as_float((u).z & 0xffff0000u); \
    acc[(o)+6] += __uint_as_float((u).w << 16); \
    acc[(o)+7] += __uint_as_float((u).w & 0xffff0000u);

#define UNPK_SET(u, o) \
    acc[(o)+0] = __uint_as_float((u).x << 16); \
    acc[(o)+1] = __uint_as_float((u).x & 0xffff0000u); \
    acc[(o)+2] = __uint_as_float((u).y << 16); \
    acc[(o)+3] = __uint_as_float((u).y & 0xffff0000u); \
    acc[(o)+4] = __uint_as_float((u).z << 16); \
    acc[(o)+5] = __uint_as_float((u).z & 0xffff0000u); \
    acc[(o)+6] = __uint_as_float((u).w << 16); \
    acc[(o)+7] = __uint_as_float((u).w & 0xffff0000u);

// ===========================================================================
// init: zero cursor (degree count) and z.
// ===========================================================================
__global__ void init_kernel(int* __restrict__ cursor, float2* __restrict__ z, int n) {
    const int i = blockIdx.x * blockDim.x + threadIdx.x;
    if (i < n) {
        cursor[i] = 0;
        z[i] = make_float2(0.f, 0.f);
    }
}

// ===========================================================================
// FUSED fill + gemm1. Independent work, block-range split:
//   blocks [0, gemmBlocks)          : y = x@W1 -> bf16 quarter-major yq
//   blocks [gemmBlocks, +fillBlocks): edge-table build (XCD dst-range filter)
// gemm blocks come FIRST so the initial dispatch wave co-schedules VALU-bound
// gemm with latency-bound fill. Zero LDS so fill occupancy isn't LDS-capped.
// ===========================================================================
__global__ __launch_bounds__(256)
void fused_fill_gemm_kernel(const float* __restrict__ x,
                            const float* __restrict__ W,    // [96][96] [k][o]
                            ushort16* __restrict__ yq,
                            const int* __restrict__ src,
                            const int* __restrict__ dst,
                            int* __restrict__ cursor,
                            int* __restrict__ srcs,
                            int n, int E, int nper,
                            int gemmBlocks, int nGroups) {
    const int blk = blockIdx.x;
    const int tid = threadIdx.x;

    if (blk < gemmBlocks) {
        // ---- gemm1 path (no LDS; x scalar loads fuse to dwordx4, W1 L2-hot
        //      wave-broadcast: 16 lanes of same quarter share each address) ----
        const int t = blk * 256 + tid;
        const int node = t >> 2;
        const int qq = t & 3;
        if (node >= n) return;

        const float* xr = x + (size_t)node * D;
        float4 oacc[6];
#pragma unroll
        for (int j = 0; j < 6; ++j) oacc[j] = make_float4(0.f, 0.f, 0.f, 0.f);
#pragma unroll 4
        for (int k = 0; k < D; ++k) {
            const float xv = xr[k];
            const float4* wrow = ((const float4*)(W + k * D)) + qq * 6;
#pragma unroll
            for (int j = 0; j < 6; ++j) {
                const float4 w = wrow[j];
                oacc[j].x += xv * w.x; oacc[j].y += xv * w.y;
                oacc[j].z += xv * w.z; oacc[j].w += xv * w.w;
            }
        }
        uint32 p[12];
#pragma unroll
        for (int j = 0; j < 6; ++j) {
            p[2 * j + 0] = pk_bf16(oacc[j].x, oacc[j].y);
            p[2 * j + 1] = pk_bf16(oacc[j].z, oacc[j].w);
        }
        uint4* dstp = (uint4*)(yq + ((size_t)qq * n + node) * 24);
        dstp[0] = make_uint4(p[0], p[1], p[2], p[3]);
        dstp[1] = make_uint4(p[4], p[5], p[6], p[7]);
        dstp[2] = make_uint4(p[8], p[9], p[10], p[11]);
    } else {
        // ---- fill path: srcs[d*CAP + p], p = atomicAdd(&cursor[d],1).
        //      XCD filter on ABSOLUTE blockIdx (&7 round-robin) keeps
        //      cursor/srcs lines XCD-local. ----
        const int xcd = blk & (NXCD - 1);
        const int g = (blk - gemmBlocks) >> 3;
        const int lo = xcd * nper, hi = lo + nper;
        const int4v* dst4 = (const int4v*)dst;
        const int quadE = E >> 2;
        for (int i = g * 256 + tid; i < quadE; i += nGroups * 256) {
            const int4v dv = __builtin_nontemporal_load(dst4 + i);
            const int e = i * 4;
            if (dv.x >= lo && dv.x < hi) {
                const int p = atomicAdd(&cursor[dv.x], 1);
                if (p < CAP) srcs[dv.x * CAP + p] = src[e];
            }
            if (dv.y >= lo && dv.y < hi) {
                const int p = atomicAdd(&cursor[dv.y], 1);
                if (p < CAP) srcs[dv.y * CAP + p] = src[e + 1];
            }
            if (dv.z >= lo && dv.z < hi) {
                const int p = atomicAdd(&cursor[dv.z], 1);
                if (p < CAP) srcs[dv.z * CAP + p] = src[e + 2];
            }
            if (dv.w >= lo && dv.w < hi) {
                const int p = atomicAdd(&cursor[dv.w], 1);
                if (p < CAP) srcs[dv.w * CAP + p] = src[e + 3];
            }
        }
        if (g == 0 && tid == 0) {
            for (int e = E & ~3; e < E; ++e) {
                const int d = dst[e];
                if (d >= lo && d < hi) {
                    const int p = atomicAdd(&cursor[d], 1);
                    if (p < CAP) srcs[d * CAP + p] = src[e];
                }
            }
        }
    }
}

// ===========================================================================
// gather1z: LANE-QUAD version. Threads {4t..4t+3} share one (node, quarter);
// lane h takes edges h, h+4, ...; acc combined via shfl_xor(1), shfl_xor(2).
// hq = relu(yq_i + sum yq_src + b1_q); z[node] += hq . W2_q.
// 64 nodes per block; quarter bound to an XCD pair via blockIdx.
// ===========================================================================
__global__ __launch_bounds__(256)
void gather1z_kernel(const ushort16* __restrict__ yq,
                     const float* __restrict__ b1,
                     const float* __restrict__ W2,
                     const int* __restrict__ cursor,
                     const int* __restrict__ srcs,
                     float* __restrict__ z,
                     int n, int bpq) {
    const int blk = blockIdx.x;
    const int q = (blk & 7) >> 1;
    const int i = ((blk >> 3) << 1) | (blk & 1);
    if (i >= bpq) return;
    const int tid = threadIdx.x;
    const int node = i * 64 + (tid >> 2);
    const int h = tid & 3;
    if (node >= n) return;

    const uint4* Y = (const uint4*)(yq + (size_t)q * n * 24);

    float acc[24];
    if (h == 0) {
        const uint4* r = Y + (size_t)node * 3;
        const uint4 u0 = r[0], u1 = r[1], u2 = r[2];
        UNPK_SET(u0, 0) UNPK_SET(u1, 8) UNPK_SET(u2, 16)
    } else {
#pragma unroll
        for (int j = 0; j < 24; ++j) acc[j] = 0.f;
    }

    const int s0 = node * CAP;
    const int deg = min(cursor[node], CAP);
    int p = h;
    for (; p + 4 < deg; p += 8) {                 // edges p and p+4
        const int sA = srcs[s0 + p];
        const int sB = srcs[s0 + p + 4];
        const uint4* rA = Y + (size_t)sA * 3;
        const uint4* rB = Y + (size_t)sB * 3;
        const uint4 a0 = rA[0], a1 = rA[1], a2 = rA[2];
        const uint4 c0 = rB[0], c1 = rB[1], c2 = rB[2];
        UNPK_ADD(a0, 0) UNPK_ADD(a1, 8) UNPK_ADD(a2, 16)
        UNPK_ADD(c0, 0) UNPK_ADD(c1, 8) UNPK_ADD(c2, 16)
    }
    if (p < deg) {
        const uint4* rA = Y + (size_t)srcs[s0 + p] * 3;
        const uint4 a0 = rA[0], a1 = rA[1], a2 = rA[2];
        UNPK_ADD(a0, 0) UNPK_ADD(a1, 8) UNPK_ADD(a2, 16)
    }

    // combine the lane quad
#pragma unroll
    for (int j = 0; j < 24; ++j) {
        acc[j] += __shfl_xor(acc[j], 1, 64);
        acc[j] += __shfl_xor(acc[j], 2, 64);
    }

    if (h == 0) {
        const float* bq = b1 + q * 24;
        const float* wq = W2 + q * 48;
        float z0 = 0.f, z1 = 0.f;
#pragma unroll
        for (int j = 0; j < 24; ++j) {
            const float hv = fmaxf(acc[j] + bq[j], 0.0f);
            z0 += hv * wq[2 * j + 0];
            z1 += hv * wq[2 * j + 1];
        }
        atomicAdd(&z[2 * node + 0], z0);
        atomicAdd(&z[2 * node + 1], z1);
    }
}

// ===========================================================================
// gather2: out = z[node] + sum_src z[src] + b2.  z is 400 KB, L2-hot.
// ===========================================================================
__global__ __launch_bounds__(256)
void gather2_kernel(const float* __restrict__ z,
                    const float* __restrict__ b,
                    const int* __restrict__ cursor,
                    const int* __restrict__ srcs,
                    float* __restrict__ out, int n) {
    const int node = blockIdx.x * blockDim.x + threadIdx.x;
    if (node >= n) return;

    const float2 zi = ((const float2*)z)[node];
    float a0 = zi.x + b[0];
    float a1 = zi.y + b[1];

    const int s0 = node * CAP;
    const int deg = min(cursor[node], CAP);
    int p = 0;
    for (; p + 2 <= deg; p += 2) {
        const float2 vA = ((const float2*)z)[srcs[s0 + p]];
        const float2 vB = ((const float2*)z)[srcs[s0 + p + 1]];
        a0 += vA.x + vB.x;
        a1 += vA.y + vB.y;
    }
    if (p < deg) {
        const float2 vA = ((const float2*)z)[srcs[s0 + p]];
        a0 += vA.x;
        a1 += vA.y;
    }
    ((float2*)out)[node] = make_float2(a0, a1);
}

// ===========================================================================
extern "C" void kernel_launch(void* const* d_in, const int* in_sizes, int n_in,
                              void* d_out, int out_size, void* d_ws, size_t ws_size,
                              hipStream_t stream) {
    const float* x   = (const float*)d_in[0];
    const int*   eix = (const int*)d_in[1];
    const float* W1  = (const float*)d_in[2];
    const float* b1  = (const float*)d_in[3];
    const float* W2  = (const float*)d_in[4];
    const float* b2  = (const float*)d_in[5];
    float*       out = (float*)d_out;

    const int n = in_sizes[0] / D;       // 50000
    const int E = in_sizes[1] / 2;       // 800000
    const int* src = eix;
    const int* dst = eix + E;

    const int nper = (n + NXCD - 1) / NXCD;   // dst range per XCD (filter only)

    // ws layout: yq (bf16, n*96) | z (f32, 2n) | cursor (n) | srcs (n*CAP)
    ushort16* yq = (ushort16*)d_ws;
    float* z     = (float*)(yq + (size_t)n * D);
    int* cursor  = (int*)(z + 2 * (size_t)n);
    int* srcs    = cursor + n;

    const int nGroups = 384;                   // fill groups per XCD
    const int gemmBlocks = (4 * n + 255) / 256;              // 782
    const int fillBlocks = nGroups * NXCD;                   // 3072

    // ---- init, then fused [gemm1 || edge-table fill] ----
    init_kernel<<<(n + 255) / 256, 256, 0, stream>>>(cursor, (float2*)z, n);
    fused_fill_gemm_kernel<<<gemmBlocks + fillBlocks, 256, 0, stream>>>(
        x, W1, yq, src, dst, cursor, srcs, n, E, nper, gemmBlocks, nGroups);

    // ---- fused gather + bias/relu + W2 projection -> z (lane-quad) ----
    const int bpq = (n + 63) / 64;
    const int g1grid = 8 * ((bpq + 1) / 2);
    gather1z_kernel<<<g1grid, 256, 0, stream>>>(yq, b1, W2, cursor, srcs, z, n, bpq);

    // ---- layer 2 gather: out = z_i + sum z_src + b2 ----
    gather2_kernel<<<(n + 255) / 256, 256, 0, stream>>>(z, b2, cursor, srcs, out, n);
}

// Round 12
// 118.771 us; speedup vs baseline: 1.2399x; 1.2399x over previous
//
#include <hip/hip_runtime.h>

#define D 96
#define D4 24
#define NT 64
#define XPAD 97
#define NXCD 8
#define CAP 64    // slots per node; P(Poisson(16) >= 64) ~ 1e-18

typedef unsigned int uint32;
typedef unsigned short ushort16;
typedef int int4v __attribute__((ext_vector_type(4)));   // clang vector (NT-load ok)

// Round-to-nearest-even f32 -> bf16, packed pair.
__device__ __forceinline__ uint32 pk_bf16(float a, float b) {
    uint32 ua = __float_as_uint(a);
    uint32 ub = __float_as_uint(b);
    ua = (ua + 0x7fffu + ((ua >> 16) & 1u)) >> 16;
    ub = (ub + 0x7fffu + ((ub >> 16) & 1u)) & 0xffff0000u;
    return (ua & 0xffffu) | ub;
}

#define UNPK_ADD(u, o) \
    acc[(o)+0] += __uint_as_float((u).x << 16); \
    acc[(o)+1] += __uint_as_float((u).x & 0xffff0000u); \
    acc[(o)+2] += __uint_as_float((u).y << 16); \
    acc[(o)+3] += __uint_as_float((u).y & 0xffff0000u); \
    acc[(o)+4] += __uint_as_float((u).z << 16); \
    acc[(o)+5] += __uint_as_float((u).z & 0xffff0000u); \
    acc[(o)+6] += __uint_as_float((u).w << 16); \
    acc[(o)+7] += __uint_as_float((u).w & 0xffff0000u);

#define UNPK_SET(u, o) \
    acc[(o)+0] = __uint_as_float((u).x << 16); \
    acc[(o)+1] = __uint_as_float((u).x & 0xffff0000u); \
    acc[(o)+2] = __uint_as_float((u).y << 16); \
    acc[(o)+3] = __uint_as_float((u).y & 0xffff0000u); \
    acc[(o)+4] = __uint_as_float((u).z << 16); \
    acc[(o)+5] = __uint_as_float((u).z & 0xffff0000u); \
    acc[(o)+6] = __uint_as_float((u).w << 16); \
    acc[(o)+7] = __uint_as_float((u).w & 0xffff0000u);

// ===========================================================================
// gemm1 + init: y = x @ W1 (bf16 quarter-major, 2.4 MB slab per quarter).
// Also zeroes cursor and z (init folded in: gemm1 touches neither, and fill
// launches strictly after this kernel completes). LDS staging of W1 is
// essential: without it the per-k W row cycle (36.9 KB) thrashes the 32 KB
// L1 (round-11 regression).
// ===========================================================================
__global__ __launch_bounds__(256, 2)
void gemm1_kernel(const float* __restrict__ x,
                  const float* __restrict__ W,
                  ushort16* __restrict__ yq,
                  int* __restrict__ cursor,
                  float2* __restrict__ z, int n) {
    __shared__ float Xs[NT][XPAD];
    __shared__ float4 Ws[D * D4];

    const int tid = threadIdx.x;

    // ---- folded init (50000 < 782*256 threads) ----
    const int t = blockIdx.x * 256 + tid;
    if (t < n) {
        cursor[t] = 0;
        z[t] = make_float2(0.f, 0.f);
    }

    for (int i = tid; i < D * D4; i += 256)
        Ws[i] = ((const float4*)W)[i];

    const int node_l = tid >> 2;
    const int qq = tid & 3;
    const int node = blockIdx.x * NT + node_l;

    if (node < n) {
        const float4* xr = ((const float4*)(x + (size_t)node * D)) + qq * 6;
#pragma unroll
        for (int j = 0; j < 6; ++j) {
            const float4 v = xr[j];
            Xs[node_l][qq * 24 + j * 4 + 0] = v.x;
            Xs[node_l][qq * 24 + j * 4 + 1] = v.y;
            Xs[node_l][qq * 24 + j * 4 + 2] = v.z;
            Xs[node_l][qq * 24 + j * 4 + 3] = v.w;
        }
    }
    __syncthreads();

    if (node < n) {
        float4 oacc[6];
#pragma unroll
        for (int j = 0; j < 6; ++j) oacc[j] = make_float4(0.f, 0.f, 0.f, 0.f);
#pragma unroll 4
        for (int k = 0; k < D; ++k) {
            const float xv = Xs[node_l][k];
            const float4* wrow = Ws + k * D4 + qq * 6;
#pragma unroll
            for (int j = 0; j < 6; ++j) {
                const float4 w = wrow[j];
                oacc[j].x += xv * w.x; oacc[j].y += xv * w.y;
                oacc[j].z += xv * w.z; oacc[j].w += xv * w.w;
            }
        }
        uint32 p[12];
#pragma unroll
        for (int j = 0; j < 6; ++j) {
            p[2 * j + 0] = pk_bf16(oacc[j].x, oacc[j].y);
            p[2 * j + 1] = pk_bf16(oacc[j].z, oacc[j].w);
        }
        uint4* dstp = (uint4*)(yq + ((size_t)qq * n + node) * 24);
        dstp[0] = make_uint4(p[0], p[1], p[2], p[3]);
        dstp[1] = make_uint4(p[4], p[5], p[6], p[7]);
        dstp[2] = make_uint4(p[8], p[9], p[10], p[11]);
    }
}

// ===========================================================================
// fill_x: one-pass edge table build. srcs[d*CAP + p], p = atomicAdd.
// XCD dst-range filter keeps cursor/srcs lines XCD-local. Unconditional
// int4v NT loads of BOTH dst and src (no dependent scalar src load).
// ===========================================================================
__global__ __launch_bounds__(256)
void fill_x_kernel(const int* __restrict__ src, const int* __restrict__ dst,
                   int* __restrict__ cursor, int* __restrict__ srcs,
                   int E, int nper, int nGroups) {
    const int xcd = blockIdx.x & (NXCD - 1);
    const int g = blockIdx.x >> 3;
    const int lo = xcd * nper, hi = lo + nper;
    const int4v* dst4 = (const int4v*)dst;
    const int4v* src4 = (const int4v*)src;
    const int quadE = E >> 2;
    for (int i = g * 256 + (int)threadIdx.x; i < quadE; i += nGroups * 256) {
        const int4v dv = __builtin_nontemporal_load(dst4 + i);
        const int4v sv = __builtin_nontemporal_load(src4 + i);
        if (dv.x >= lo && dv.x < hi) {
            const int p = atomicAdd(&cursor[dv.x], 1);
            if (p < CAP) srcs[dv.x * CAP + p] = sv.x;
        }
        if (dv.y >= lo && dv.y < hi) {
            const int p = atomicAdd(&cursor[dv.y], 1);
            if (p < CAP) srcs[dv.y * CAP + p] = sv.y;
        }
        if (dv.z >= lo && dv.z < hi) {
            const int p = atomicAdd(&cursor[dv.z], 1);
            if (p < CAP) srcs[dv.z * CAP + p] = sv.z;
        }
        if (dv.w >= lo && dv.w < hi) {
            const int p = atomicAdd(&cursor[dv.w], 1);
            if (p < CAP) srcs[dv.w * CAP + p] = sv.w;
        }
    }
    if (g == 0 && threadIdx.x == 0) {
        for (int e = E & ~3; e < E; ++e) {
            const int d = dst[e];
            if (d >= lo && d < hi) {
                const int p = atomicAdd(&cursor[d], 1);
                if (p < CAP) srcs[d * CAP + p] = src[e];
            }
        }
    }
}

// ===========================================================================
// gather1z: lane-quad. Threads {4t..4t+3} share one (node, quarter); lane h
// takes edges h, h+4, ...; acc combined via shfl_xor(1), shfl_xor(2).
// hq = relu(yq_i + sum yq_src + b1_q); z[node] += hq . W2_q.
// Quarter bound to an XCD pair via blockIdx for y-slab L2 residency.
// ===========================================================================
__global__ __launch_bounds__(256)
void gather1z_kernel(const ushort16* __restrict__ yq,
                     const float* __restrict__ b1,
                     const float* __restrict__ W2,
                     const int* __restrict__ cursor,
                     const int* __restrict__ srcs,
                     float* __restrict__ z,
                     int n, int bpq) {
    const int blk = blockIdx.x;
    const int q = (blk & 7) >> 1;
    const int i = ((blk >> 3) << 1) | (blk & 1);
    if (i >= bpq) return;
    const int tid = threadIdx.x;
    const int node = i * 64 + (tid >> 2);
    const int h = tid & 3;
    if (node >= n) return;

    const uint4* Y = (const uint4*)(yq + (size_t)q * n * 24);

    float acc[24];
    if (h == 0) {
        const uint4* r = Y + (size_t)node * 3;
        const uint4 u0 = r[0], u1 = r[1], u2 = r[2];
        UNPK_SET(u0, 0) UNPK_SET(u1, 8) UNPK_SET(u2, 16)
    } else {
#pragma unroll
        for (int j = 0; j < 24; ++j) acc[j] = 0.f;
    }

    const int s0 = node * CAP;
    const int deg = min(cursor[node], CAP);
    int p = h;
    for (; p + 4 < deg; p += 8) {                 // edges p and p+4
        const int sA = srcs[s0 + p];
        const int sB = srcs[s0 + p + 4];
        const uint4* rA = Y + (size_t)sA * 3;
        const uint4* rB = Y + (size_t)sB * 3;
        const uint4 a0 = rA[0], a1 = rA[1], a2 = rA[2];
        const uint4 c0 = rB[0], c1 = rB[1], c2 = rB[2];
        UNPK_ADD(a0, 0) UNPK_ADD(a1, 8) UNPK_ADD(a2, 16)
        UNPK_ADD(c0, 0) UNPK_ADD(c1, 8) UNPK_ADD(c2, 16)
    }
    if (p < deg) {
        const uint4* rA = Y + (size_t)srcs[s0 + p] * 3;
        const uint4 a0 = rA[0], a1 = rA[1], a2 = rA[2];
        UNPK_ADD(a0, 0) UNPK_ADD(a1, 8) UNPK_ADD(a2, 16)
    }

#pragma unroll
    for (int j = 0; j < 24; ++j) {
        acc[j] += __shfl_xor(acc[j], 1, 64);
        acc[j] += __shfl_xor(acc[j], 2, 64);
    }

    if (h == 0) {
        const float* bq = b1 + q * 24;
        const float* wq = W2 + q * 48;
        float z0 = 0.f, z1 = 0.f;
#pragma unroll
        for (int j = 0; j < 24; ++j) {
            const float hv = fmaxf(acc[j] + bq[j], 0.0f);
            z0 += hv * wq[2 * j + 0];
            z1 += hv * wq[2 * j + 1];
        }
        atomicAdd(&z[2 * node + 0], z0);
        atomicAdd(&z[2 * node + 1], z1);
    }
}

// ===========================================================================
// gather2: out = z[node] + sum_src z[src] + b2.  z is 400 KB, L2-hot.
// ===========================================================================
__global__ __launch_bounds__(256)
void gather2_kernel(const float* __restrict__ z,
                    const float* __restrict__ b,
                    const int* __restrict__ cursor,
                    const int* __restrict__ srcs,
                    float* __restrict__ out, int n) {
    const int node = blockIdx.x * blockDim.x + threadIdx.x;
    if (node >= n) return;

    const float2 zi = ((const float2*)z)[node];
    float a0 = zi.x + b[0];
    float a1 = zi.y + b[1];

    const int s0 = node * CAP;
    const int deg = min(cursor[node], CAP);
    int p = 0;
    for (; p + 2 <= deg; p += 2) {
        const float2 vA = ((const float2*)z)[srcs[s0 + p]];
        const float2 vB = ((const float2*)z)[srcs[s0 + p + 1]];
        a0 += vA.x + vB.x;
        a1 += vA.y + vB.y;
    }
    if (p < deg) {
        const float2 vA = ((const float2*)z)[srcs[s0 + p]];
        a0 += vA.x;
        a1 += vA.y;
    }
    ((float2*)out)[node] = make_float2(a0, a1);
}

// ===========================================================================
extern "C" void kernel_launch(void* const* d_in, const int* in_sizes, int n_in,
                              void* d_out, int out_size, void* d_ws, size_t ws_size,
                              hipStream_t stream) {
    const float* x   = (const float*)d_in[0];
    const int*   eix = (const int*)d_in[1];
    const float* W1  = (const float*)d_in[2];
    const float* b1  = (const float*)d_in[3];
    const float* W2  = (const float*)d_in[4];
    const float* b2  = (const float*)d_in[5];
    float*       out = (float*)d_out;

    const int n = in_sizes[0] / D;       // 50000
    const int E = in_sizes[1] / 2;       // 800000
    const int* src = eix;
    const int* dst = eix + E;

    const int nper = (n + NXCD - 1) / NXCD;   // dst range per XCD (filter only)

    // ws layout: yq (bf16, n*96) | z (f32, 2n) | cursor (n) | srcs (n*CAP)
    ushort16* yq = (ushort16*)d_ws;
    float* z     = (float*)(yq + (size_t)n * D);
    int* cursor  = (int*)(z + 2 * (size_t)n);
    int* srcs    = cursor + n;

    const int nGroups = 384;                   // fill groups per XCD

    // ---- gemm1 (+ folded init of cursor/z): y = x@W1, bf16 quarter-major ----
    const int tiles = (n + NT - 1) / NT;       // 782
    gemm1_kernel<<<tiles, 256, 0, stream>>>(x, W1, yq, cursor, (float2*)z, n);

    // ---- edge-table build ----
    fill_x_kernel<<<nGroups * NXCD, 256, 0, stream>>>(src, dst, cursor, srcs, E, nper, nGroups);

    // ---- fused gather + bias/relu + W2 projection -> z (lane-quad) ----
    const int bpq = (n + 63) / 64;
    const int g1grid = 8 * ((bpq + 1) / 2);
    gather1z_kernel<<<g1grid, 256, 0, stream>>>(yq, b1, W2, cursor, srcs, z, n, bpq);

    // ---- layer 2 gather: out = z_i + sum z_src + b2 ----
    gather2_kernel<<<(n + 255) / 256, 256, 0, stream>>>(z, b2, cursor, srcs, out, n);
}

// Round 13
// 117.705 us; speedup vs baseline: 1.2511x; 1.0091x over previous
//
#include <hip/hip_runtime.h>

#define D 96
#define D4 24
#define NT 64
#define XPAD 97
#define NXCD 8
#define CAP 64    // slots per node; P(Poisson(16) >= 64) ~ 1e-18

typedef unsigned int uint32;
typedef unsigned short ushort16;
typedef int int4v __attribute__((ext_vector_type(4)));   // clang vector (NT-load ok)

// Round-to-nearest-even f32 -> bf16, packed pair.
__device__ __forceinline__ uint32 pk_bf16(float a, float b) {
    uint32 ua = __float_as_uint(a);
    uint32 ub = __float_as_uint(b);
    ua = (ua + 0x7fffu + ((ua >> 16) & 1u)) >> 16;
    ub = (ub + 0x7fffu + ((ub >> 16) & 1u)) & 0xffff0000u;
    return (ua & 0xffffu) | ub;
}

#define UNPK_ADD(u, o) \
    acc[(o)+0] += __uint_as_float((u).x << 16); \
    acc[(o)+1] += __uint_as_float((u).x & 0xffff0000u); \
    acc[(o)+2] += __uint_as_float((u).y << 16); \
    acc[(o)+3] += __uint_as_float((u).y & 0xffff0000u); \
    acc[(o)+4] += __uint_as_float((u).z << 16); \
    acc[(o)+5] += __uint_as_float((u).z & 0xffff0000u); \
    acc[(o)+6] += __uint_as_float((u).w << 16); \
    acc[(o)+7] += __uint_as_float((u).w & 0xffff0000u);

#define UNPK_SET(u, o) \
    acc[(o)+0] = __uint_as_float((u).x << 16); \
    acc[(o)+1] = __uint_as_float((u).x & 0xffff0000u); \
    acc[(o)+2] = __uint_as_float((u).y << 16); \
    acc[(o)+3] = __uint_as_float((u).y & 0xffff0000u); \
    acc[(o)+4] = __uint_as_float((u).z << 16); \
    acc[(o)+5] = __uint_as_float((u).z & 0xffff0000u); \
    acc[(o)+6] = __uint_as_float((u).w << 16); \
    acc[(o)+7] = __uint_as_float((u).w & 0xffff0000u);

// ===========================================================================
// gemm1 + init: y = x @ W1 (bf16 quarter-major). Also zeroes cursor/z.
// LDS staging of W1 essential (round-11: no-LDS variant thrashes 32 KB L1).
// ===========================================================================
__global__ __launch_bounds__(256, 2)
void gemm1_kernel(const float* __restrict__ x,
                  const float* __restrict__ W,
                  ushort16* __restrict__ yq,
                  int* __restrict__ cursor,
                  float2* __restrict__ z, int n) {
    __shared__ float Xs[NT][XPAD];
    __shared__ float4 Ws[D * D4];

    const int tid = threadIdx.x;

    const int t = blockIdx.x * 256 + tid;
    if (t < n) {
        cursor[t] = 0;
        z[t] = make_float2(0.f, 0.f);
    }

    for (int i = tid; i < D * D4; i += 256)
        Ws[i] = ((const float4*)W)[i];

    const int node_l = tid >> 2;
    const int qq = tid & 3;
    const int node = blockIdx.x * NT + node_l;

    if (node < n) {
        const float4* xr = ((const float4*)(x + (size_t)node * D)) + qq * 6;
#pragma unroll
        for (int j = 0; j < 6; ++j) {
            const float4 v = xr[j];
            Xs[node_l][qq * 24 + j * 4 + 0] = v.x;
            Xs[node_l][qq * 24 + j * 4 + 1] = v.y;
            Xs[node_l][qq * 24 + j * 4 + 2] = v.z;
            Xs[node_l][qq * 24 + j * 4 + 3] = v.w;
        }
    }
    __syncthreads();

    if (node < n) {
        float4 oacc[6];
#pragma unroll
        for (int j = 0; j < 6; ++j) oacc[j] = make_float4(0.f, 0.f, 0.f, 0.f);
#pragma unroll 4
        for (int k = 0; k < D; ++k) {
            const float xv = Xs[node_l][k];
            const float4* wrow = Ws + k * D4 + qq * 6;
#pragma unroll
            for (int j = 0; j < 6; ++j) {
                const float4 w = wrow[j];
                oacc[j].x += xv * w.x; oacc[j].y += xv * w.y;
                oacc[j].z += xv * w.z; oacc[j].w += xv * w.w;
            }
        }
        uint32 p[12];
#pragma unroll
        for (int j = 0; j < 6; ++j) {
            p[2 * j + 0] = pk_bf16(oacc[j].x, oacc[j].y);
            p[2 * j + 1] = pk_bf16(oacc[j].z, oacc[j].w);
        }
        uint4* dstp = (uint4*)(yq + ((size_t)qq * n + node) * 24);
        dstp[0] = make_uint4(p[0], p[1], p[2], p[3]);
        dstp[1] = make_uint4(p[4], p[5], p[6], p[7]);
        dstp[2] = make_uint4(p[8], p[9], p[10], p[11]);
    }
}

// ===========================================================================
// fill_x: one-pass edge table build. srcs[d*CAP + p], p = atomicAdd.
// XCD dst-range filter keeps cursor/srcs lines XCD-local. nGroups=1024 ->
// each thread handles <= 1 quad-iteration: per-thread serial chain is a
// single {NT load -> atomic -> store}; latency hidden by wave TLP.
// ===========================================================================
__global__ __launch_bounds__(256)
void fill_x_kernel(const int* __restrict__ src, const int* __restrict__ dst,
                   int* __restrict__ cursor, int* __restrict__ srcs,
                   int E, int nper, int nGroups) {
    const int xcd = blockIdx.x & (NXCD - 1);
    const int g = blockIdx.x >> 3;
    const int lo = xcd * nper, hi = lo + nper;
    const int4v* dst4 = (const int4v*)dst;
    const int4v* src4 = (const int4v*)src;
    const int quadE = E >> 2;
    for (int i = g * 256 + (int)threadIdx.x; i < quadE; i += nGroups * 256) {
        const int4v dv = __builtin_nontemporal_load(dst4 + i);
        const int4v sv = __builtin_nontemporal_load(src4 + i);
        if (dv.x >= lo && dv.x < hi) {
            const int p = atomicAdd(&cursor[dv.x], 1);
            if (p < CAP) srcs[dv.x * CAP + p] = sv.x;
        }
        if (dv.y >= lo && dv.y < hi) {
            const int p = atomicAdd(&cursor[dv.y], 1);
            if (p < CAP) srcs[dv.y * CAP + p] = sv.y;
        }
        if (dv.z >= lo && dv.z < hi) {
            const int p = atomicAdd(&cursor[dv.z], 1);
            if (p < CAP) srcs[dv.z * CAP + p] = sv.z;
        }
        if (dv.w >= lo && dv.w < hi) {
            const int p = atomicAdd(&cursor[dv.w], 1);
            if (p < CAP) srcs[dv.w * CAP + p] = sv.w;
        }
    }
    if (g == 0 && threadIdx.x == 0) {
        for (int e = E & ~3; e < E; ++e) {
            const int d = dst[e];
            if (d >= lo && d < hi) {
                const int p = atomicAdd(&cursor[d], 1);
                if (p < CAP) srcs[d * CAP + p] = src[e];
            }
        }
    }
}

// ===========================================================================
// gather1z: lane-quad, 4-deep unrolled. Threads {4t..4t+3} share one
// (node, quarter); lane h takes edges h+4k. Typical node (deg~16 -> 4
// edges/lane) completes in ONE iteration with 4 row-loads in flight.
// hq = relu(yq_i + sum yq_src + b1_q); z[node] += hq . W2_q.
// ===========================================================================
__global__ __launch_bounds__(256)
void gather1z_kernel(const ushort16* __restrict__ yq,
                     const float* __restrict__ b1,
                     const float* __restrict__ W2,
                     const int* __restrict__ cursor,
                     const int* __restrict__ srcs,
                     float* __restrict__ z,
                     int n, int bpq) {
    const int blk = blockIdx.x;
    const int q = (blk & 7) >> 1;
    const int i = ((blk >> 3) << 1) | (blk & 1);
    if (i >= bpq) return;
    const int tid = threadIdx.x;
    const int node = i * 64 + (tid >> 2);
    const int h = tid & 3;
    if (node >= n) return;

    const uint4* Y = (const uint4*)(yq + (size_t)q * n * 24);

    float acc[24];
    if (h == 0) {
        const uint4* r = Y + (size_t)node * 3;
        const uint4 u0 = r[0], u1 = r[1], u2 = r[2];
        UNPK_SET(u0, 0) UNPK_SET(u1, 8) UNPK_SET(u2, 16)
    } else {
#pragma unroll
        for (int j = 0; j < 24; ++j) acc[j] = 0.f;
    }

    const int s0 = node * CAP;
    const int deg = min(cursor[node], CAP);
    int p = h;
    // 4-deep: edges p, p+4, p+8, p+12
    for (; p + 12 < deg; p += 16) {
        const int sA = srcs[s0 + p];
        const int sB = srcs[s0 + p + 4];
        const int sC = srcs[s0 + p + 8];
        const int sD = srcs[s0 + p + 12];
        const uint4* rA = Y + (size_t)sA * 3;
        const uint4* rB = Y + (size_t)sB * 3;
        const uint4* rC = Y + (size_t)sC * 3;
        const uint4* rD = Y + (size_t)sD * 3;
        const uint4 a0 = rA[0], a1 = rA[1], a2 = rA[2];
        const uint4 c0 = rB[0], c1 = rB[1], c2 = rB[2];
        const uint4 e0 = rC[0], e1 = rC[1], e2 = rC[2];
        const uint4 f0 = rD[0], f1 = rD[1], f2 = rD[2];
        UNPK_ADD(a0, 0) UNPK_ADD(a1, 8) UNPK_ADD(a2, 16)
        UNPK_ADD(c0, 0) UNPK_ADD(c1, 8) UNPK_ADD(c2, 16)
        UNPK_ADD(e0, 0) UNPK_ADD(e1, 8) UNPK_ADD(e2, 16)
        UNPK_ADD(f0, 0) UNPK_ADD(f1, 8) UNPK_ADD(f2, 16)
    }
    // 2-deep remainder
    for (; p + 4 < deg; p += 8) {
        const int sA = srcs[s0 + p];
        const int sB = srcs[s0 + p + 4];
        const uint4* rA = Y + (size_t)sA * 3;
        const uint4* rB = Y + (size_t)sB * 3;
        const uint4 a0 = rA[0], a1 = rA[1], a2 = rA[2];
        const uint4 c0 = rB[0], c1 = rB[1], c2 = rB[2];
        UNPK_ADD(a0, 0) UNPK_ADD(a1, 8) UNPK_ADD(a2, 16)
        UNPK_ADD(c0, 0) UNPK_ADD(c1, 8) UNPK_ADD(c2, 16)
    }
    if (p < deg) {
        const uint4* rA = Y + (size_t)srcs[s0 + p] * 3;
        const uint4 a0 = rA[0], a1 = rA[1], a2 = rA[2];
        UNPK_ADD(a0, 0) UNPK_ADD(a1, 8) UNPK_ADD(a2, 16)
    }

#pragma unroll
    for (int j = 0; j < 24; ++j) {
        acc[j] += __shfl_xor(acc[j], 1, 64);
        acc[j] += __shfl_xor(acc[j], 2, 64);
    }

    if (h == 0) {
        const float* bq = b1 + q * 24;
        const float* wq = W2 + q * 48;
        float z0 = 0.f, z1 = 0.f;
#pragma unroll
        for (int j = 0; j < 24; ++j) {
            const float hv = fmaxf(acc[j] + bq[j], 0.0f);
            z0 += hv * wq[2 * j + 0];
            z1 += hv * wq[2 * j + 1];
        }
        atomicAdd(&z[2 * node + 0], z0);
        atomicAdd(&z[2 * node + 1], z1);
    }
}

// ===========================================================================
// gather2: out = z[node] + sum_src z[src] + b2.  z is 400 KB, L2-hot.
// ===========================================================================
__global__ __launch_bounds__(256)
void gather2_kernel(const float* __restrict__ z,
                    const float* __restrict__ b,
                    const int* __restrict__ cursor,
                    const int* __restrict__ srcs,
                    float* __restrict__ out, int n) {
    const int node = blockIdx.x * blockDim.x + threadIdx.x;
    if (node >= n) return;

    const float2 zi = ((const float2*)z)[node];
    float a0 = zi.x + b[0];
    float a1 = zi.y + b[1];

    const int s0 = node * CAP;
    const int deg = min(cursor[node], CAP);
    int p = 0;
    for (; p + 2 <= deg; p += 2) {
        const float2 vA = ((const float2*)z)[srcs[s0 + p]];
        const float2 vB = ((const float2*)z)[srcs[s0 + p + 1]];
        a0 += vA.x + vB.x;
        a1 += vA.y + vB.y;
    }
    if (p < deg) {
        const float2 vA = ((const float2*)z)[srcs[s0 + p]];
        a0 += vA.x;
        a1 += vA.y;
    }
    ((float2*)out)[node] = make_float2(a0, a1);
}

// ===========================================================================
extern "C" void kernel_launch(void* const* d_in, const int* in_sizes, int n_in,
                              void* d_out, int out_size, void* d_ws, size_t ws_size,
                              hipStream_t stream) {
    const float* x   = (const float*)d_in[0];
    const int*   eix = (const int*)d_in[1];
    const float* W1  = (const float*)d_in[2];
    const float* b1  = (const float*)d_in[3];
    const float* W2  = (const float*)d_in[4];
    const float* b2  = (const float*)d_in[5];
    float*       out = (float*)d_out;

    const int n = in_sizes[0] / D;       // 50000
    const int E = in_sizes[1] / 2;       // 800000
    const int* src = eix;
    const int* dst = eix + E;

    const int nper = (n + NXCD - 1) / NXCD;   // dst range per XCD (filter only)

    // ws layout: yq (bf16, n*96) | z (f32, 2n) | cursor (n) | srcs (n*CAP)
    ushort16* yq = (ushort16*)d_ws;
    float* z     = (float*)(yq + (size_t)n * D);
    int* cursor  = (int*)(z + 2 * (size_t)n);
    int* srcs    = cursor + n;

    const int nGroups = 1024;                  // fill groups per XCD (TLP probe)

    // ---- gemm1 (+ folded init of cursor/z): y = x@W1, bf16 quarter-major ----
    const int tiles = (n + NT - 1) / NT;       // 782
    gemm1_kernel<<<tiles, 256, 0, stream>>>(x, W1, yq, cursor, (float2*)z, n);

    // ---- edge-table build ----
    fill_x_kernel<<<nGroups * NXCD, 256, 0, stream>>>(src, dst, cursor, srcs, E, nper, nGroups);

    // ---- fused gather + bias/relu + W2 projection -> z (lane-quad, 4-deep) ----
    const int bpq = (n + 63) / 64;
    const int g1grid = 8 * ((bpq + 1) / 2);
    gather1z_kernel<<<g1grid, 256, 0, stream>>>(yq, b1, W2, cursor, srcs, z, n, bpq);

    // ---- layer 2 gather: out = z_i + sum z_src + b2 ----
    gather2_kernel<<<(n + 255) / 256, 256, 0, stream>>>(z, b2, cursor, srcs, out, n);
}